// Round 14
// baseline (647.401 us; speedup 1.0000x reference)
//
#include <hip/hip_runtime.h>

typedef __attribute__((ext_vector_type(8))) _Float16 f16x8;
typedef __attribute__((ext_vector_type(4))) _Float16 f16x4;
typedef __attribute__((ext_vector_type(2))) _Float16 f16x2;
typedef __attribute__((ext_vector_type(2))) __fp16 fp16x2_n;
typedef __attribute__((ext_vector_type(8))) short bf16x8;
typedef __attribute__((ext_vector_type(4))) float f32x4;
typedef __attribute__((ext_vector_type(4))) unsigned short u16x4;
typedef __attribute__((ext_vector_type(4))) float fx4;

#define D_MODEL 1024
#define N_HEADS 16
#define SEQ 2048
#define TOKENS 4096
#define N_EXP 8
#define EHID 512
#define LO_S 2048.0f
#define INV_LO (1.0f / 2048.0f)
#define QSCALE 0.18033688011112043f   // 0.125 * log2(e) folded into Q
#define DTHR 11.0f                    // defer-max threshold (log2 domain)

__device__ inline unsigned short f2bf(float f) {
  union { float f; unsigned u; } v; v.f = f;
  unsigned u = v.u;
  return (unsigned short)((u + 0x7FFFu + ((u >> 16) & 1u)) >> 16);
}

__device__ inline float bf2f(unsigned short b) {
  union { unsigned u; float f; } v; v.u = ((unsigned)b) << 16;
  return v.f;
}

__device__ inline void split16(float v, _Float16& h, _Float16& l) {
  h = (_Float16)v;
  l = (_Float16)((v - (float)h) * LO_S);
}

__device__ inline void split2(float a, float b, f16x2& h, f16x2& l) {
  fp16x2_n hn = __builtin_amdgcn_cvt_pkrtz(a, b);
  h = __builtin_bit_cast(f16x2, hn);
  fp16x2_n ln = __builtin_amdgcn_cvt_pkrtz((a - (float)h[0]) * LO_S, (b - (float)h[1]) * LO_S);
  l = __builtin_bit_cast(f16x2, ln);
}

__device__ inline void gload_lds16(const void* g, void* lds) {
  __builtin_amdgcn_global_load_lds((const __attribute__((address_space(1))) void*)g,
                                   (__attribute__((address_space(3))) void*)lds, 16, 0, 0);
}

// ---------------- fused LN1 + all weight transposes + routing init (one launch) ----------------
__global__ __launch_bounds__(256) void prep_ln_kernel(const float* __restrict__ x, const float* __restrict__ g1,
                                                      const float* __restrict__ b1,
                                                      _Float16* __restrict__ xh, _Float16* __restrict__ xl,
                                                      const float* __restrict__ Wq, const float* __restrict__ Wk,
                                                      const float* __restrict__ Wv, const float* __restrict__ Wo,
                                                      const float* __restrict__ W1, const float* __restrict__ W2,
                                                      _Float16* __restrict__ qkvh, _Float16* __restrict__ qkvl,
                                                      _Float16* __restrict__ woh, _Float16* __restrict__ wol,
                                                      unsigned short* __restrict__ W1T, unsigned short* __restrict__ W2T,
                                                      int* __restrict__ cnt, int* __restrict__ cnt8,
                                                      int* __restrict__ perm) {
  int bb = blockIdx.x;
  if (bb < 4096) {          // ---- LN1 ----
    int t = bb, tid = threadIdx.x;
    const float* row = x + (size_t)t * D_MODEL;
    fx4 v = *(const fx4*)(row + tid * 4);
    float s = v[0] + v[1] + v[2] + v[3];
    float s2 = v[0]*v[0] + v[1]*v[1] + v[2]*v[2] + v[3]*v[3];
    #pragma unroll
    for (int off = 1; off < 64; off <<= 1) { s += __shfl_xor(s, off); s2 += __shfl_xor(s2, off); }
    __shared__ float red[8];
    int wv = tid >> 6, wl = tid & 63;
    if (wl == 0) { red[wv] = s; red[4 + wv] = s2; }
    __syncthreads();
    s = red[0] + red[1] + red[2] + red[3];
    s2 = red[4] + red[5] + red[6] + red[7];
    float mu = s * (1.f / 1024.f);
    float var = s2 * (1.f / 1024.f) - mu * mu;
    float rstd = rsqrtf(var + 1e-5f);
    int kk = tid * 4;
    f16x4 oh, ol;
    #pragma unroll
    for (int c = 0; c < 4; c++) {
      float y = (v[c] - mu) * rstd * g1[kk + c] + b1[kk + c];
      _Float16 h, lo; split16(y, h, lo);
      oh[c] = h; ol[c] = lo;
    }
    *(f16x4*)(xh + (size_t)t * D_MODEL + kk) = oh;
    *(f16x4*)(xl + (size_t)t * D_MODEL + kk) = ol;
    return;
  }
  int b = bb - 4096;
  if (b >= 12288) {
    int i = (b - 12288) * 256 + threadIdx.x;
    if (i < 8) cnt[i] = 0;
    if (i < 64) cnt8[i] = 0;
    if (i < 8704) perm[i] = 0;
    return;
  }
  __shared__ float tile[32][33];
  int tx = threadIdx.x & 31, ty = threadIdx.x >> 5;
  if (b < 4096) {
    int z = b >> 10, rem = b & 1023;
    int c0 = (rem & 31) * 32, r0 = (rem >> 5) * 32;
    const float* src = (z == 0) ? Wq : (z == 1) ? Wk : (z == 2) ? Wv : Wo;
    _Float16* dh = (z < 3) ? qkvh + (size_t)z * 1048576 : woh;
    _Float16* dl = (z < 3) ? qkvl + (size_t)z * 1048576 : wol;
    #pragma unroll
    for (int i = 0; i < 4; i++) tile[ty + 8*i][tx] = src[(size_t)(r0 + ty + 8*i) * 1024 + c0 + tx];
    __syncthreads();
    #pragma unroll
    for (int i = 0; i < 4; i++) {
      float v = tile[tx][ty + 8*i];
      _Float16 h, lo; split16(v, h, lo);
      size_t idx = (size_t)(c0 + ty + 8*i) * 1024 + r0 + tx;
      dh[idx] = h; dl[idx] = lo;
    }
  } else if (b < 8192) {
    int q = b - 4096, z = q >> 9, rem = q & 511;
    int c0 = (rem & 15) * 32, r0 = (rem >> 4) * 32;
    const float* src = W1 + (size_t)z * 524288;
    unsigned short* dst = W1T + (size_t)z * 524288;
    #pragma unroll
    for (int i = 0; i < 4; i++) tile[ty + 8*i][tx] = src[(size_t)(r0 + ty + 8*i) * 512 + c0 + tx];
    __syncthreads();
    #pragma unroll
    for (int i = 0; i < 4; i++) dst[(size_t)(c0 + ty + 8*i) * 1024 + r0 + tx] = f2bf(tile[tx][ty + 8*i]);
  } else {
    int q = b - 8192, z = q >> 9, rem = q & 511;
    int c0 = (rem & 31) * 32, r0 = (rem >> 5) * 32;
    const float* src = W2 + (size_t)z * 524288;
    unsigned short* dst = W2T + (size_t)z * 524288;
    #pragma unroll
    for (int i = 0; i < 4; i++) tile[ty + 8*i][tx] = src[(size_t)(r0 + ty + 8*i) * 1024 + c0 + tx];
    __syncthreads();
    #pragma unroll
    for (int i = 0; i < 4; i++) dst[(size_t)(c0 + ty + 8*i) * 512 + r0 + tx] = f2bf(tile[tx][ty + 8*i]);
  }
}

// ---------------- split-fp16 128x128 GEMM core, double-buffered 2-phase pipeline ----------------
__device__ inline void gemm128s(const _Float16* __restrict__ Ah, const _Float16* __restrict__ Al,
                                const _Float16* __restrict__ Bh, const _Float16* __restrict__ Bl,
                                int lda, int ldb, int K, int bm, int bn,
                                _Float16* lsbuf, f32x4 (&acc)[4][4], f32x4 (&accx)[4][4]) {
  const int tid = threadIdx.x, w = tid >> 6, l = tid & 63, lr = l & 15, lg = l >> 4;
  const int wr = (w >> 1) * 64, wc = (w & 1) * 64;
  int ca = (((tid & 3) ^ ((tid >> 3) & 3)) * 8);
  int ra0 = tid >> 2, ra1 = 64 + (tid >> 2);
  const _Float16* gA0 = Ah + (size_t)(bm + ra0) * lda + ca;
  const _Float16* gA1 = Ah + (size_t)(bm + ra1) * lda + ca;
  const _Float16* gA2 = Al + (size_t)(bm + ra0) * lda + ca;
  const _Float16* gA3 = Al + (size_t)(bm + ra1) * lda + ca;
  const _Float16* gB0 = Bh + (size_t)(bn + ra0) * ldb + ca;
  const _Float16* gB1 = Bh + (size_t)(bn + ra1) * ldb + ca;
  const _Float16* gB2 = Bl + (size_t)(bn + ra0) * ldb + ca;
  const _Float16* gB3 = Bl + (size_t)(bn + ra1) * ldb + ca;
  char* base = (char*)lsbuf;
  const int wo = w * 1024;
#define STAGE8(bb_, ko) do { \
    gload_lds16(gA0 + (ko), (bb_) + wo);         gload_lds16(gA1 + (ko), (bb_) + 4096 + wo);  \
    gload_lds16(gA2 + (ko), (bb_) + 8192 + wo);  gload_lds16(gA3 + (ko), (bb_) + 12288 + wo); \
    gload_lds16(gB0 + (ko), (bb_) + 16384 + wo); gload_lds16(gB1 + (ko), (bb_) + 20480 + wo); \
    gload_lds16(gB2 + (ko), (bb_) + 24576 + wo); gload_lds16(gB3 + (ko), (bb_) + 28672 + wo); } while (0)
  STAGE8(base, 0);
  __syncthreads();
  const int swzB = ((lg ^ ((lr >> 1) & 3)) << 4);
  int cur = 0;
  for (int ko = 0; ko < K; ko += 32) {
    char* bR = base + cur * 32768;
    if (ko + 32 < K) STAGE8(base + (cur ^ 1) * 32768, ko + 32);
    f16x8 ah[4], al4[4], bh4[4], bl4[4];
    #pragma unroll
    for (int m = 0; m < 4; m++) {
      int roff = (wr + m * 16 + lr) * 64 + swzB;
      ah[m]  = *(const f16x8*)(bR + roff);
      al4[m] = *(const f16x8*)(bR + 8192 + roff);
    }
    #pragma unroll
    for (int n = 0; n < 4; n++) {
      int roff = (wc + n * 16 + lr) * 64 + swzB;
      bh4[n] = *(const f16x8*)(bR + 16384 + roff);
      bl4[n] = *(const f16x8*)(bR + 24576 + roff);
    }
    __builtin_amdgcn_s_setprio(1);
    #pragma unroll
    for (int m = 0; m < 4; m++)
      #pragma unroll
      for (int n = 0; n < 4; n++) {
        acc[m][n]  = __builtin_amdgcn_mfma_f32_16x16x32_f16(ah[m], bh4[n], acc[m][n], 0, 0, 0);
        accx[m][n] = __builtin_amdgcn_mfma_f32_16x16x32_f16(ah[m], bl4[n], accx[m][n], 0, 0, 0);
        accx[m][n] = __builtin_amdgcn_mfma_f32_16x16x32_f16(al4[m], bh4[n], accx[m][n], 0, 0, 0);
      }
    __builtin_amdgcn_s_setprio(0);
    __syncthreads();
    cur ^= 1;
  }
#undef STAGE8
}

// ---------------- QKV GEMM -> q plain (pre-scaled), K/V^T in swizzled 2048-elem tiles ----------------
__global__ __launch_bounds__(256) void gemm_qkv_kernel(const _Float16* __restrict__ xh, const _Float16* __restrict__ xl,
                                                       const _Float16* __restrict__ Wh, const _Float16* __restrict__ Wl,
                                                       _Float16* __restrict__ qh, _Float16* __restrict__ ql,
                                                       _Float16* __restrict__ kh, _Float16* __restrict__ kl,
                                                       _Float16* __restrict__ vh, _Float16* __restrict__ vl) {
  __shared__ _Float16 ls[32768];
  f32x4 acc[4][4] = {}, accx[4][4] = {};
  int bid = blockIdx.x;
  int sw = (bid & 7) * 96 + (bid >> 3);
  int bm = (sw & 31) * 128, bn = (sw >> 5) * 128;
  gemm128s(xh, xl, Wh, Wl, 1024, 1024, 1024, bm, bn, ls, acc, accx);
  const int tid = threadIdx.x, w = tid >> 6, l = tid & 63, lr = l & 15, lg = l >> 4;
  const int wr = (w >> 1) * 64, wc = (w & 1) * 64;
  #pragma unroll
  for (int m = 0; m < 4; m++) {
    int row0 = bm + wr + m * 16 + lg * 4;
    #pragma unroll
    for (int n = 0; n < 4; n++) {
      int col = bn + wc + n * 16 + lr;
      int mat = col >> 10;
      int c = col & 1023, h = c >> 6, d = c & 63;
      if (mat == 2) {
        int bb = row0 >> 11, ss = row0 & 2047;
        int tile = ss >> 5, kvs = ss & 31;
        f16x4 ph, pl;
        #pragma unroll
        for (int j = 0; j < 4; j++) {
          float v = acc[m][n][j] + accx[m][n][j] * INV_LO;
          _Float16 hh, ll; split16(v, hh, ll);
          ph[j] = hh; pl[j] = ll;
        }
        size_t base = ((size_t)(bb * N_HEADS + h) * 64 + tile) * 2048;
        int off = d * 32 + ((((kvs >> 3) ^ ((d >> 1) & 3)) << 3) | (kvs & 7));
        *(f16x4*)(vh + base + off) = ph;
        *(f16x4*)(vl + base + off) = pl;
      } else if (mat == 1) {
        #pragma unroll
        for (int j = 0; j < 4; j++) {
          float v = acc[m][n][j] + accx[m][n][j] * INV_LO;
          _Float16 hh, ll; split16(v, hh, ll);
          int t = row0 + j, bb = t >> 11, ss = t & 2047;
          int tile = ss >> 5, r = ss & 31;
          size_t base = ((size_t)(bb * N_HEADS + h) * 64 + tile) * 2048;
          int off = r * 64 + ((((d >> 3) ^ (r & 7)) << 3) | (d & 7));
          kh[base + off] = hh; kl[base + off] = ll;
        }
      } else {
        #pragma unroll
        for (int j = 0; j < 4; j++) {
          float v = (acc[m][n][j] + accx[m][n][j] * INV_LO) * QSCALE;
          _Float16 hh, ll; split16(v, hh, ll);
          int t = row0 + j, bb = t >> 11, ss = t & 2047;
          size_t idx = ((size_t)(bb * N_HEADS + h) * SEQ + ss) * 64 + d;
          qh[idx] = hh; ql[idx] = ll;
        }
      }
    }
  }
}

// ---------------- Flash attention: 2 sequential 64q tiles per block share KV staging ----------------
__global__ __launch_bounds__(256, 4) void flash_kernel(const _Float16* __restrict__ qhp, const _Float16* __restrict__ qlp,
                                                       const _Float16* __restrict__ khs, const _Float16* __restrict__ kls,
                                                       const _Float16* __restrict__ vhs, const _Float16* __restrict__ vls,
                                                       _Float16* __restrict__ oh, _Float16* __restrict__ ol) {
  __shared__ _Float16 lsKV[2][8192];
  __shared__ _Float16 lsP[4][2][512];
  int wgid = blockIdx.x;
  int xcd = wgid & 7, kk = wgid >> 3;          // 512 blocks: 64/XCD
  int bh = xcd * 4 + (kk >> 4), qt = kk & 15;  // 4 heads/XCD, 16 x 128q supertiles
  int tid = threadIdx.x, w = tid >> 6, l = tid & 63, lr = l & 15, lg = l >> 4;
  int q0 = qt * 128 + w * 16;                  // tile A rows; tile B = q0 + 64
  const _Float16* qhb = qhp + (size_t)bh * SEQ * 64;
  const _Float16* qlb = qlp + (size_t)bh * SEQ * 64;
  f16x8 qfh[2][2], qfl[2][2];                  // [tq][ks]
  #pragma unroll
  for (int tq = 0; tq < 2; tq++)
    #pragma unroll
    for (int ks = 0; ks < 2; ks++) {
      size_t idx = (size_t)(q0 + tq * 64 + lr) * 64 + ks * 32 + lg * 8;
      qfh[tq][ks] = *(const f16x8*)(qhb + idx);
      qfl[tq][ks] = *(const f16x8*)(qlb + idx);
    }
  const _Float16* splane = (w == 0) ? khs : (w == 1) ? kls : (w == 2) ? vhs : vls;
  const _Float16* sbase = splane + (size_t)bh * 131072 + l * 8;

  f32x4 acc[2][4] = {}, accx[2][4] = {};       // [tq][m2]
  float mst[2] = {-1e30f, -1e30f}, lstp[2] = {0.f, 0.f};

  {
    const _Float16* sp = sbase;
    _Float16* dd = &lsKV[0][w * 2048];
    gload_lds16(sp, dd); gload_lds16(sp + 512, dd + 512);
    gload_lds16(sp + 1024, dd + 1024); gload_lds16(sp + 1536, dd + 1536);
  }
  __syncthreads();

  for (int t = 0; t < 64; t++) {
    int bR = t & 1;
    if (t < 63) {
      const _Float16* sp = sbase + (size_t)(t + 1) * 2048;
      _Float16* dd = &lsKV[bR ^ 1][w * 2048];
      gload_lds16(sp, dd); gload_lds16(sp + 512, dd + 512);
      gload_lds16(sp + 1024, dd + 1024); gload_lds16(sp + 1536, dd + 1536);
    }
    char* bufB = (char*)&lsKV[bR][0];

    #pragma unroll
    for (int tq = 0; tq < 2; tq++) {
      // ---- QK^T ----
      f32x4 s[2] = {}, sx[2] = {};
      #pragma unroll
      for (int ks = 0; ks < 2; ks++) {
        f16x8 kfh[2], kfl[2];
        #pragma unroll
        for (int m = 0; m < 2; m++) {
          int off = (m * 16 + lr) * 128 + (((ks * 4 + lg) ^ (lr & 7)) << 4);
          kfh[m] = *(const f16x8*)(bufB + off);
          kfl[m] = *(const f16x8*)(bufB + 4096 + off);
        }
        __builtin_amdgcn_s_setprio(1);
        #pragma unroll
        for (int m = 0; m < 2; m++) {
          s[m]  = __builtin_amdgcn_mfma_f32_16x16x32_f16(kfh[m], qfh[tq][ks], s[m], 0, 0, 0);
          sx[m] = __builtin_amdgcn_mfma_f32_16x16x32_f16(kfh[m], qfl[tq][ks], sx[m], 0, 0, 0);
          sx[m] = __builtin_amdgcn_mfma_f32_16x16x32_f16(kfl[m], qfh[tq][ks], sx[m], 0, 0, 0);
        }
        __builtin_amdgcn_s_setprio(0);
      }

      // ---- softmax ----
      float tm = -3e38f;
      #pragma unroll
      for (int m = 0; m < 2; m++)
        #pragma unroll
        for (int j = 0; j < 4; j++) {
          s[m][j] += sx[m][j] * INV_LO;
          tm = fmaxf(tm, s[m][j]);
        }
      if (!__all(tm - mst[tq] <= DTHR)) {
        tm = fmaxf(tm, __shfl_xor(tm, 16));
        tm = fmaxf(tm, __shfl_xor(tm, 32));
        float mnew = fmaxf(mst[tq], tm);
        float corr = exp2f(mst[tq] - mnew);
        #pragma unroll
        for (int m2 = 0; m2 < 4; m2++)
          #pragma unroll
          for (int j = 0; j < 4; j++) { acc[tq][m2][j] *= corr; accx[tq][m2][j] *= corr; }
        lstp[tq] *= corr;
        mst[tq] = mnew;
      }
      #pragma unroll
      for (int m = 0; m < 2; m++) {
        #pragma unroll
        for (int j = 0; j < 4; j++) {
          float p = exp2f(s[m][j] - mst[tq]);
          lstp[tq] += p;
          s[m][j] = p;
        }
        f16x2 h01, h23, l01, l23;
        split2(s[m][0], s[m][1], h01, l01);
        split2(s[m][2], s[m][3], h23, l23);
        f16x4 ph, pl;
        ph[0] = h01[0]; ph[1] = h01[1]; ph[2] = h23[0]; ph[3] = h23[1];
        pl[0] = l01[0]; pl[1] = l01[1]; pl[2] = l23[0]; pl[3] = l23[1];
        int boff = lr * 64 + ((((m * 2 + (lg >> 1)) ^ ((lr >> 1) & 3)) << 4) | ((lg & 1) * 8));
        *(f16x4*)((char*)&lsP[w][0][0] + boff) = ph;
        *(f16x4*)((char*)&lsP[w][1][0] + boff) = pl;
      }

      // ---- PV ----
      int poff = lr * 64 + ((lg ^ ((lr >> 1) & 3)) << 4);
      f16x8 pfh = *(const f16x8*)((char*)&lsP[w][0][0] + poff);
      f16x8 pfl = *(const f16x8*)((char*)&lsP[w][1][0] + poff);
      __builtin_amdgcn_s_setprio(1);
      #pragma unroll
      for (int m2 = 0; m2 < 4; m2++) {
        int voff = (m2 * 16 + lr) * 64 + ((lg ^ ((lr >> 1) & 3)) << 4);
        f16x8 vfh = *(const f16x8*)(bufB + 8192 + voff);
        f16x8 vfl = *(const f16x8*)(bufB + 12288 + voff);
        acc[tq][m2]  = __builtin_amdgcn_mfma_f32_16x16x32_f16(vfh, pfh, acc[tq][m2], 0, 0, 0);
        accx[tq][m2] = __builtin_amdgcn_mfma_f32_16x16x32_f16(vfh, pfl, accx[tq][m2], 0, 0, 0);
        accx[tq][m2] = __builtin_amdgcn_mfma_f32_16x16x32_f16(vfl, pfh, accx[tq][m2], 0, 0, 0);
      }
      __builtin_amdgcn_s_setprio(0);
    }
    __syncthreads();
  }

  int b = bh >> 4, h = bh & 15;
  #pragma unroll
  for (int tq = 0; tq < 2; tq++) {
    float lst = lstp[tq] + __shfl_xor(lstp[tq], 16);
    lst += __shfl_xor(lst, 32);
    float inv = 1.f / lst;
    int tkn = b * SEQ + q0 + tq * 64 + lr;
    #pragma unroll
    for (int m2 = 0; m2 < 4; m2++) {
      f16x4 ph, pl;
      #pragma unroll
      for (int j = 0; j < 4; j++) {
        float o = (acc[tq][m2][j] + accx[tq][m2][j] * INV_LO) * inv;
        _Float16 hh, ll; split16(o, hh, ll);
        ph[j] = hh; pl[j] = ll;
      }
      size_t idx = (size_t)tkn * D_MODEL + h * 64 + m2 * 16 + lg * 4;
      *(f16x4*)(oh + idx) = ph;
      *(f16x4*)(ol + idx) = pl;
    }
  }
}

// ---------------- O-proj GEMM + residual -> d_out (fp32) ----------------
__global__ __launch_bounds__(256) void gemm_oproj_kernel(const _Float16* __restrict__ ah, const _Float16* __restrict__ al,
                                                         const _Float16* __restrict__ Wh, const _Float16* __restrict__ Wl,
                                                         const float* __restrict__ x, float* __restrict__ out) {
  __shared__ _Float16 ls[32768];
  f32x4 acc[4][4] = {}, accx[4][4] = {};
  int bid = blockIdx.x;
  int sw = (bid & 7) * 32 + (bid >> 3);
  int bm = (sw & 31) * 128, bn = (sw >> 5) * 128;
  gemm128s(ah, al, Wh, Wl, 1024, 1024, 1024, bm, bn, ls, acc, accx);
  const int tid = threadIdx.x, w = tid >> 6, l = tid & 63, lr = l & 15, lg = l >> 4;
  const int wr = (w >> 1) * 64, wc = (w & 1) * 64;
  #pragma unroll
  for (int m = 0; m < 4; m++) {
    int row0 = bm + wr + m * 16 + lg * 4;
    #pragma unroll
    for (int n = 0; n < 4; n++) {
      int col = bn + wc + n * 16 + lr;
      #pragma unroll
      for (int j = 0; j < 4; j++) {
        size_t idx = (size_t)(row0 + j) * D_MODEL + col;
        out[idx] = (acc[m][n][j] + accx[m][n][j] * INV_LO) + x[idx];
      }
    }
  }
}

// ---------------- fused LN2 + xn2(bf16) + gate + top2 (fp32) ----------------
__global__ __launch_bounds__(256) void gate_kernel(const float* __restrict__ x1, const float* __restrict__ Wg,
                                                   const float* __restrict__ g2, const float* __restrict__ b2,
                                                   unsigned short* __restrict__ xn2,
                                                   int* __restrict__ cnt, int* __restrict__ cnt8,
                                                   int* __restrict__ topi, float* __restrict__ topw) {
  int t = blockIdx.x * 4 + (threadIdx.x >> 6);
  int l = threadIdx.x & 63;
  const float* row = x1 + (size_t)t * D_MODEL;
  fx4 v[4];
  float s = 0.f, s2 = 0.f;
  #pragma unroll
  for (int i = 0; i < 4; i++) {
    v[i] = *(const fx4*)(row + l * 16 + i * 4);
    #pragma unroll
    for (int c = 0; c < 4; c++) { s += v[i][c]; s2 += v[i][c] * v[i][c]; }
  }
  #pragma unroll
  for (int off = 1; off < 64; off <<= 1) { s += __shfl_xor(s, off); s2 += __shfl_xor(s2, off); }
  float mu = s * (1.f / 1024.f);
  float var = s2 * (1.f / 1024.f) - mu * mu;
  float rstd = rsqrtf(var + 1e-5f);
  float a8[8] = {0,0,0,0,0,0,0,0};
  #pragma unroll
  for (int i = 0; i < 4; i++) {
    u16x4 ox;
    #pragma unroll
    for (int c = 0; c < 4; c++) {
      int kk = l * 16 + i * 4 + c;
      float xv = (v[i][c] - mu) * rstd * g2[kk] + b2[kk];
      ox[c] = f2bf(xv);
      const float* wr_ = Wg + (size_t)kk * 8;
      fx4 wa = *(const fx4*)wr_;
      fx4 wb = *(const fx4*)(wr_ + 4);
      a8[0] += xv * wa[0]; a8[1] += xv * wa[1]; a8[2] += xv * wa[2]; a8[3] += xv * wa[3];
      a8[4] += xv * wb[0]; a8[5] += xv * wb[1]; a8[6] += xv * wb[2]; a8[7] += xv * wb[3];
    }
    *(u16x4*)(xn2 + (size_t)t * D_MODEL + l * 16 + i * 4) = ox;
  }
  #pragma unroll
  for (int e = 0; e < 8; e++)
    #pragma unroll
    for (int off = 1; off < 64; off <<= 1) a8[e] += __shfl_xor(a8[e], off);
  if (l == 0) {
    int i0 = 0; float v0 = a8[0];
    #pragma unroll
    for (int e = 1; e < 8; e++) if (a8[e] > v0) { v0 = a8[e]; i0 = e; }
    int i1 = -1; float v1 = -3.4e38f;
    #pragma unroll
    for (int e = 0; e < 8; e++) if (e != i0 && a8[e] > v1) { v1 = a8[e]; i1 = e; }
    float p0 = 1.f / (1.f + __expf(v1 - v0));
    topi[t * 2] = i0; topi[t * 2 + 1] = i1;
    topw[t * 2] = p0; topw[t * 2 + 1] = 1.f - p0;
    int seg = t >> 9;
    atomicAdd(&cnt[i0], 1); atomicAdd(&cnt[i1], 1);
    atomicAdd(&cnt8[i0 * 8 + seg], 1); atomicAdd(&cnt8[i1 * 8 + seg], 1);
  }
}

// stable partition of the 8192 (token,k) assignments; block = (expert, 512-token segment)
__global__ __launch_bounds__(256) void scatter_kernel(const int* __restrict__ topi, const int* __restrict__ cnt,
                                                      const int* __restrict__ cnt8,
                                                      int* __restrict__ perm, int* __restrict__ slot_of) {
  int e = blockIdx.x & 7, seg = blockIdx.x >> 3;
  int tid = threadIdx.x;
  __shared__ int basesh;
  __shared__ int wsum[4];
  if (tid == 0) {
    int a = 0;
    for (int i = 0; i < e; i++) a += ((cnt[i] + 63) >> 6) << 6;
    for (int s = 0; s < seg; s++) a += cnt8[e * 8 + s];
    basesh = a;
  }
  __syncthreads();
  int a0 = seg * 1024;
  for (int segi = 0; segi < 1024; segi += 256) {
    int a = a0 + segi + tid;
    int match = (topi[a] == e) ? 1 : 0;
    unsigned long long bal = __ballot(match);
    int wl = tid & 63, wv = tid >> 6;
    int lanepre = __popcll(bal & ((1ULL << wl) - 1ULL));
    if (wl == 0) wsum[wv] = __popcll(bal);
    __syncthreads();
    int wpre = 0;
    for (int i = 0; i < wv; i++) wpre += wsum[i];
    int total = wsum[0] + wsum[1] + wsum[2] + wsum[3];
    if (match) {
      int pos = basesh + wpre + lanepre;
      perm[pos] = a >> 1;
      slot_of[a] = pos;
    }
    __syncthreads();
    if (tid == 0) basesh += total;
    __syncthreads();
  }
}

// ---------------- MoE FFN: 64-token tile, 8 waves, hid in 2 halves, writes y[slot][1024] (bf16) ----------------
__global__ __launch_bounds__(512) void moe_ffn_kernel(const unsigned short* __restrict__ xn2,
                                                      const unsigned short* __restrict__ W1T,
                                                      const unsigned short* __restrict__ W2T,
                                                      const int* __restrict__ cnt,
                                                      const int* __restrict__ perm,
                                                      unsigned short* __restrict__ y) {
  int bid = blockIdx.x;
  int e = -1, lt = bid, off = 0;
  for (int i = 0; i < 8; i++) {
    int nt = (cnt[i] + 63) >> 6;
    if (lt < nt) { e = i; break; }
    lt -= nt; off += nt << 6;
  }
  if (e < 0) return;
  int slot0 = off + lt * 64;

  __shared__ int t_sh[64];
  __shared__ unsigned short lsX[64 * 128];
  __shared__ unsigned short hsh[64 * 264];
  int tid = threadIdx.x, w = tid >> 6, l = tid & 63, lr = l & 15, lg = l >> 4;
  if (tid < 64) t_sh[tid] = perm[slot0 + tid];
  __syncthreads();

  const unsigned short* W1e = W1T + (size_t)e * EHID * D_MODEL;
  const unsigned short* W2e = W2T + (size_t)e * D_MODEL * EHID;

  f32x4 acc2[4][8] = {};
  for (int h = 0; h < 2; h++) {
    f32x4 acc1[4][2] = {};
    for (int kc = 0; kc < 8; kc++) {
      __syncthreads();
      #pragma unroll
      for (int L = 0; L < 2; L++) {
        int u = tid + 512 * L;
        int r = u >> 4, sp = u & 15;
        int cs = (sp & 8) | ((sp & 7) ^ (r & 7));
        gload_lds16(xn2 + (size_t)t_sh[r] * D_MODEL + kc * 128 + cs * 8, (char*)lsX + u * 16);
      }
      __syncthreads();
      #pragma unroll
      for (int kst = 0; kst < 4; kst++) {
        bf16x8 a[4];
        #pragma unroll
        for (int m = 0; m < 4; m++) {
          int row = m * 16 + lr;
          int slot = kst * 4 + lg;
          int cs = (slot & 8) | ((slot & 7) ^ (row & 7));
          a[m] = *(const bf16x8*)((char*)lsX + row * 256 + cs * 16);
        }
        int ko = kc * 128 + kst * 32;
        #pragma unroll
        for (int n = 0; n < 2; n++) {
          bf16x8 bb = *(const bf16x8*)(W1e + (size_t)(h * 256 + w * 32 + n * 16 + lr) * D_MODEL + ko + lg * 8);
          #pragma unroll
          for (int m = 0; m < 4; m++)
            acc1[m][n] = __builtin_amdgcn_mfma_f32_16x16x32_bf16(a[m], bb, acc1[m][n], 0, 0, 0);
        }
      }
    }
    __syncthreads();
    #pragma unroll
    for (int m = 0; m < 4; m++)
      #pragma unroll
      for (int n = 0; n < 2; n++)
        #pragma unroll
        for (int j = 0; j < 4; j++)
          hsh[(m*16 + lg*4 + j) * 264 + w * 32 + n * 16 + lr] = f2bf(fmaxf(acc1[m][n][j], 0.f));
    __syncthreads();
    for (int k2 = 0; k2 < 256; k2 += 32) {
      bf16x8 a2[4];
      #pragma unroll
      for (int m = 0; m < 4; m++) a2[m] = *(const bf16x8*)(hsh + (m*16 + lr) * 264 + k2 + lg * 8);
      #pragma unroll
      for (int n = 0; n < 8; n++) {
        bf16x8 bb = *(const bf16x8*)(W2e + (size_t)(w * 128 + n * 16 + lr) * EHID + h * 256 + k2 + lg * 8);
        #pragma unroll
        for (int m = 0; m < 4; m++)
          acc2[m][n] = __builtin_amdgcn_mfma_f32_16x16x32_bf16(a2[m], bb, acc2[m][n], 0, 0, 0);
      }
    }
  }
  #pragma unroll
  for (int m = 0; m < 4; m++)
    #pragma unroll
    for (int j = 0; j < 4; j++) {
      int r = m * 16 + lg * 4 + j;
      #pragma unroll
      for (int n = 0; n < 8; n++)
        y[(size_t)(slot0 + r) * D_MODEL + w * 128 + n * 16 + lr] = f2bf(acc2[m][n][j]);
    }
}

// ---------------- combine: out[t] += w0*y[s0] + w1*y[s1] (y bf16) ----------------
__global__ __launch_bounds__(256) void combine_kernel(const unsigned short* __restrict__ y, const int* __restrict__ slot_of,
                                                      const float* __restrict__ topw, float* __restrict__ out) {
  int t = blockIdx.x * 4 + (threadIdx.x >> 6);
  int l = threadIdx.x & 63;
  int s0 = slot_of[t * 2], s1 = slot_of[t * 2 + 1];
  float w0 = topw[t * 2], w1 = topw[t * 2 + 1];
  const unsigned short* y0 = y + (size_t)s0 * D_MODEL + l * 16;
  const unsigned short* y1 = y + (size_t)s1 * D_MODEL + l * 16;
  float* o = out + (size_t)t * D_MODEL + l * 16;
  #pragma unroll
  for (int i = 0; i < 4; i++) {
    u16x4 av = *(const u16x4*)(y0 + i * 4);
    u16x4 bv = *(const u16x4*)(y1 + i * 4);
    fx4 d = *(const fx4*)(o + i * 4);
    #pragma unroll
    for (int j = 0; j < 4; j++) d[j] += w0 * bf2f(av[j]) + w1 * bf2f(bv[j]);
    *(fx4*)(o + i * 4) = d;
  }
}

// ---------------- launcher ----------------
#define MB (1u << 20)
extern "C" void kernel_launch(void* const* d_in, const int* in_sizes, int n_in,
                              void* d_out, int out_size, void* d_ws, size_t ws_size,
                              hipStream_t stream) {
  const float* x  = (const float*)d_in[0];
  const float* Wq = (const float*)d_in[1];
  const float* Wk = (const float*)d_in[2];
  const float* Wv = (const float*)d_in[3];
  const float* Wo = (const float*)d_in[4];
  const float* g1 = (const float*)d_in[5];
  const float* b1 = (const float*)d_in[6];
  const float* g2 = (const float*)d_in[7];
  const float* b2 = (const float*)d_in[8];
  const float* Wg = (const float*)d_in[9];
  const float* W1 = (const float*)d_in[10];
  const float* W2 = (const float*)d_in[11];
  float* out = (float*)d_out;

  char* ws = (char*)d_ws;
  _Float16* xn1h = (_Float16*)(ws + 0*MB);     // later aliased as attn hi plane
  _Float16* xn1l = (_Float16*)(ws + 8*MB);     // later aliased as attn lo plane
  _Float16* Wqkh = (_Float16*)(ws + 16*MB);
  _Float16* Wqkl = (_Float16*)(ws + 22*MB);
  _Float16* Woh  = (_Float16*)(ws + 28*MB);
  _Float16* Wol  = (_Float16*)(ws + 30*MB);
  _Float16* qhb  = (_Float16*)(ws + 32*MB);
  _Float16* qlb  = (_Float16*)(ws + 40*MB);
  _Float16* khb  = (_Float16*)(ws + 48*MB);
  _Float16* klb  = (_Float16*)(ws + 56*MB);
  _Float16* vhb  = (_Float16*)(ws + 64*MB);
  _Float16* vlb  = (_Float16*)(ws + 72*MB);
  unsigned short* xn2 = (unsigned short*)(ws + 80*MB);
  unsigned short* W1T = (unsigned short*)(ws + 88*MB);
  unsigned short* W2T = (unsigned short*)(ws + 96*MB);
  char* misc = ws + 104*MB;
  int*   topi    = (int*)(misc);
  float* topw    = (float*)(misc + 32768);
  int*   slot_of = (int*)(misc + 65536);
  int*   cnt     = (int*)(misc + 98304);
  int*   cnt8    = (int*)(misc + 98368);
  int*   perm    = (int*)(misc + 98688);
  unsigned short* ybuf = (unsigned short*)(ws + 32*MB);   // bf16 y, aliases q/k/v (dead after flash)
  _Float16* attnh = xn1h;
  _Float16* attnl = xn1l;

  // fused LN1 + weight prep + routing init (one launch)
  prep_ln_kernel<<<16419, 256, 0, stream>>>(x, g1, b1, xn1h, xn1l,
                                            Wq, Wk, Wv, Wo, W1, W2,
                                            Wqkh, Wqkl, Woh, Wol, W1T, W2T, cnt, cnt8, perm);

  // attention path (split fp16, ~fp32 accuracy)
  gemm_qkv_kernel<<<768, 256, 0, stream>>>(xn1h, xn1l, Wqkh, Wqkl, qhb, qlb, khb, klb, vhb, vlb);
  flash_kernel<<<512, 256, 0, stream>>>(qhb, qlb, khb, klb, vhb, vlb, attnh, attnl);
  gemm_oproj_kernel<<<256, 256, 0, stream>>>(attnh, attnl, Woh, Wol, x, out);

  // MoE path
  gate_kernel<<<1024, 256, 0, stream>>>(out, Wg, g2, b2, xn2, cnt, cnt8, topi, topw);
  scatter_kernel<<<64, 256, 0, stream>>>(topi, cnt, cnt8, perm, slot_of);
  moe_ffn_kernel<<<136, 512, 0, stream>>>(xn2, W1T, W2T, cnt, perm, ybuf);
  combine_kernel<<<1024, 256, 0, stream>>>(ybuf, slot_of, topw, out);

  (void)in_sizes; (void)n_in; (void)out_size; (void)ws_size;
}

// Round 15
// 516.121 us; speedup vs baseline: 1.2544x; 1.2544x over previous
//
#include <hip/hip_runtime.h>

typedef __attribute__((ext_vector_type(8))) _Float16 f16x8;
typedef __attribute__((ext_vector_type(4))) _Float16 f16x4;
typedef __attribute__((ext_vector_type(2))) _Float16 f16x2;
typedef __attribute__((ext_vector_type(2))) __fp16 fp16x2_n;
typedef __attribute__((ext_vector_type(8))) short bf16x8;
typedef __attribute__((ext_vector_type(4))) float f32x4;
typedef __attribute__((ext_vector_type(4))) unsigned short u16x4;
typedef __attribute__((ext_vector_type(4))) float fx4;

#define D_MODEL 1024
#define N_HEADS 16
#define SEQ 2048
#define TOKENS 4096
#define N_EXP 8
#define EHID 512
#define LO_S 2048.0f
#define INV_LO (1.0f / 2048.0f)
#define QSCALE 0.18033688011112043f   // 0.125 * log2(e) folded into Q
#define DTHR 11.0f                    // defer-max threshold (log2 domain)

__device__ inline unsigned short f2bf(float f) {
  union { float f; unsigned u; } v; v.f = f;
  unsigned u = v.u;
  return (unsigned short)((u + 0x7FFFu + ((u >> 16) & 1u)) >> 16);
}

__device__ inline float bf2f(unsigned short b) {
  union { unsigned u; float f; } v; v.u = ((unsigned)b) << 16;
  return v.f;
}

__device__ inline void split16(float v, _Float16& h, _Float16& l) {
  h = (_Float16)v;
  l = (_Float16)((v - (float)h) * LO_S);
}

__device__ inline void split2(float a, float b, f16x2& h, f16x2& l) {
  fp16x2_n hn = __builtin_amdgcn_cvt_pkrtz(a, b);
  h = __builtin_bit_cast(f16x2, hn);
  fp16x2_n ln = __builtin_amdgcn_cvt_pkrtz((a - (float)h[0]) * LO_S, (b - (float)h[1]) * LO_S);
  l = __builtin_bit_cast(f16x2, ln);
}

__device__ inline void gload_lds16(const void* g, void* lds) {
  __builtin_amdgcn_global_load_lds((const __attribute__((address_space(1))) void*)g,
                                   (__attribute__((address_space(3))) void*)lds, 16, 0, 0);
}

// ---------------- fused LN1 + all weight transposes + routing init (one launch) ----------------
__global__ __launch_bounds__(256) void prep_ln_kernel(const float* __restrict__ x, const float* __restrict__ g1,
                                                      const float* __restrict__ b1,
                                                      _Float16* __restrict__ xh, _Float16* __restrict__ xl,
                                                      const float* __restrict__ Wq, const float* __restrict__ Wk,
                                                      const float* __restrict__ Wv, const float* __restrict__ Wo,
                                                      const float* __restrict__ W1, const float* __restrict__ W2,
                                                      _Float16* __restrict__ qkvh, _Float16* __restrict__ qkvl,
                                                      _Float16* __restrict__ woh, _Float16* __restrict__ wol,
                                                      unsigned short* __restrict__ W1T, unsigned short* __restrict__ W2T,
                                                      int* __restrict__ cnt, int* __restrict__ cnt8,
                                                      int* __restrict__ perm) {
  int bb = blockIdx.x;
  if (bb < 4096) {          // ---- LN1 ----
    int t = bb, tid = threadIdx.x;
    const float* row = x + (size_t)t * D_MODEL;
    fx4 v = *(const fx4*)(row + tid * 4);
    float s = v[0] + v[1] + v[2] + v[3];
    float s2 = v[0]*v[0] + v[1]*v[1] + v[2]*v[2] + v[3]*v[3];
    #pragma unroll
    for (int off = 1; off < 64; off <<= 1) { s += __shfl_xor(s, off); s2 += __shfl_xor(s2, off); }
    __shared__ float red[8];
    int wv = tid >> 6, wl = tid & 63;
    if (wl == 0) { red[wv] = s; red[4 + wv] = s2; }
    __syncthreads();
    s = red[0] + red[1] + red[2] + red[3];
    s2 = red[4] + red[5] + red[6] + red[7];
    float mu = s * (1.f / 1024.f);
    float var = s2 * (1.f / 1024.f) - mu * mu;
    float rstd = rsqrtf(var + 1e-5f);
    int kk = tid * 4;
    f16x4 oh, ol;
    #pragma unroll
    for (int c = 0; c < 4; c++) {
      float y = (v[c] - mu) * rstd * g1[kk + c] + b1[kk + c];
      _Float16 h, lo; split16(y, h, lo);
      oh[c] = h; ol[c] = lo;
    }
    *(f16x4*)(xh + (size_t)t * D_MODEL + kk) = oh;
    *(f16x4*)(xl + (size_t)t * D_MODEL + kk) = ol;
    return;
  }
  int b = bb - 4096;
  if (b >= 12288) {
    int i = (b - 12288) * 256 + threadIdx.x;
    if (i < 8) cnt[i] = 0;
    if (i < 64) cnt8[i] = 0;
    if (i < 8704) perm[i] = 0;
    return;
  }
  __shared__ float tile[32][33];
  int tx = threadIdx.x & 31, ty = threadIdx.x >> 5;
  if (b < 4096) {
    int z = b >> 10, rem = b & 1023;
    int c0 = (rem & 31) * 32, r0 = (rem >> 5) * 32;
    const float* src = (z == 0) ? Wq : (z == 1) ? Wk : (z == 2) ? Wv : Wo;
    _Float16* dh = (z < 3) ? qkvh + (size_t)z * 1048576 : woh;
    _Float16* dl = (z < 3) ? qkvl + (size_t)z * 1048576 : wol;
    #pragma unroll
    for (int i = 0; i < 4; i++) tile[ty + 8*i][tx] = src[(size_t)(r0 + ty + 8*i) * 1024 + c0 + tx];
    __syncthreads();
    #pragma unroll
    for (int i = 0; i < 4; i++) {
      float v = tile[tx][ty + 8*i];
      _Float16 h, lo; split16(v, h, lo);
      size_t idx = (size_t)(c0 + ty + 8*i) * 1024 + r0 + tx;
      dh[idx] = h; dl[idx] = lo;
    }
  } else if (b < 8192) {
    int q = b - 4096, z = q >> 9, rem = q & 511;
    int c0 = (rem & 15) * 32, r0 = (rem >> 4) * 32;
    const float* src = W1 + (size_t)z * 524288;
    unsigned short* dst = W1T + (size_t)z * 524288;
    #pragma unroll
    for (int i = 0; i < 4; i++) tile[ty + 8*i][tx] = src[(size_t)(r0 + ty + 8*i) * 512 + c0 + tx];
    __syncthreads();
    #pragma unroll
    for (int i = 0; i < 4; i++) dst[(size_t)(c0 + ty + 8*i) * 1024 + r0 + tx] = f2bf(tile[tx][ty + 8*i]);
  } else {
    int q = b - 8192, z = q >> 9, rem = q & 511;
    int c0 = (rem & 31) * 32, r0 = (rem >> 5) * 32;
    const float* src = W2 + (size_t)z * 524288;
    unsigned short* dst = W2T + (size_t)z * 524288;
    #pragma unroll
    for (int i = 0; i < 4; i++) tile[ty + 8*i][tx] = src[(size_t)(r0 + ty + 8*i) * 1024 + c0 + tx];
    __syncthreads();
    #pragma unroll
    for (int i = 0; i < 4; i++) dst[(size_t)(c0 + ty + 8*i) * 512 + r0 + tx] = f2bf(tile[tx][ty + 8*i]);
  }
}

// ---------------- split-fp16 128x128 GEMM core, double-buffered 2-phase pipeline ----------------
__device__ inline void gemm128s(const _Float16* __restrict__ Ah, const _Float16* __restrict__ Al,
                                const _Float16* __restrict__ Bh, const _Float16* __restrict__ Bl,
                                int lda, int ldb, int K, int bm, int bn,
                                _Float16* lsbuf, f32x4 (&acc)[4][4], f32x4 (&accx)[4][4]) {
  const int tid = threadIdx.x, w = tid >> 6, l = tid & 63, lr = l & 15, lg = l >> 4;
  const int wr = (w >> 1) * 64, wc = (w & 1) * 64;
  int ca = (((tid & 3) ^ ((tid >> 3) & 3)) * 8);
  int ra0 = tid >> 2, ra1 = 64 + (tid >> 2);
  const _Float16* gA0 = Ah + (size_t)(bm + ra0) * lda + ca;
  const _Float16* gA1 = Ah + (size_t)(bm + ra1) * lda + ca;
  const _Float16* gA2 = Al + (size_t)(bm + ra0) * lda + ca;
  const _Float16* gA3 = Al + (size_t)(bm + ra1) * lda + ca;
  const _Float16* gB0 = Bh + (size_t)(bn + ra0) * ldb + ca;
  const _Float16* gB1 = Bh + (size_t)(bn + ra1) * ldb + ca;
  const _Float16* gB2 = Bl + (size_t)(bn + ra0) * ldb + ca;
  const _Float16* gB3 = Bl + (size_t)(bn + ra1) * ldb + ca;
  char* base = (char*)lsbuf;
  const int wo = w * 1024;
#define STAGE8(bb_, ko) do { \
    gload_lds16(gA0 + (ko), (bb_) + wo);         gload_lds16(gA1 + (ko), (bb_) + 4096 + wo);  \
    gload_lds16(gA2 + (ko), (bb_) + 8192 + wo);  gload_lds16(gA3 + (ko), (bb_) + 12288 + wo); \
    gload_lds16(gB0 + (ko), (bb_) + 16384 + wo); gload_lds16(gB1 + (ko), (bb_) + 20480 + wo); \
    gload_lds16(gB2 + (ko), (bb_) + 24576 + wo); gload_lds16(gB3 + (ko), (bb_) + 28672 + wo); } while (0)
  STAGE8(base, 0);
  __syncthreads();
  const int swzB = ((lg ^ ((lr >> 1) & 3)) << 4);
  int cur = 0;
  for (int ko = 0; ko < K; ko += 32) {
    char* bR = base + cur * 32768;
    if (ko + 32 < K) STAGE8(base + (cur ^ 1) * 32768, ko + 32);
    f16x8 ah[4], al4[4], bh4[4], bl4[4];
    #pragma unroll
    for (int m = 0; m < 4; m++) {
      int roff = (wr + m * 16 + lr) * 64 + swzB;
      ah[m]  = *(const f16x8*)(bR + roff);
      al4[m] = *(const f16x8*)(bR + 8192 + roff);
    }
    #pragma unroll
    for (int n = 0; n < 4; n++) {
      int roff = (wc + n * 16 + lr) * 64 + swzB;
      bh4[n] = *(const f16x8*)(bR + 16384 + roff);
      bl4[n] = *(const f16x8*)(bR + 24576 + roff);
    }
    __builtin_amdgcn_s_setprio(1);
    #pragma unroll
    for (int m = 0; m < 4; m++)
      #pragma unroll
      for (int n = 0; n < 4; n++) {
        acc[m][n]  = __builtin_amdgcn_mfma_f32_16x16x32_f16(ah[m], bh4[n], acc[m][n], 0, 0, 0);
        accx[m][n] = __builtin_amdgcn_mfma_f32_16x16x32_f16(ah[m], bl4[n], accx[m][n], 0, 0, 0);
        accx[m][n] = __builtin_amdgcn_mfma_f32_16x16x32_f16(al4[m], bh4[n], accx[m][n], 0, 0, 0);
      }
    __builtin_amdgcn_s_setprio(0);
    __syncthreads();
    cur ^= 1;
  }
#undef STAGE8
}

// ---------------- QKV GEMM -> q plain (pre-scaled), K/V^T in swizzled 2048-elem tiles ----------------
__global__ __launch_bounds__(256) void gemm_qkv_kernel(const _Float16* __restrict__ xh, const _Float16* __restrict__ xl,
                                                       const _Float16* __restrict__ Wh, const _Float16* __restrict__ Wl,
                                                       _Float16* __restrict__ qh, _Float16* __restrict__ ql,
                                                       _Float16* __restrict__ kh, _Float16* __restrict__ kl,
                                                       _Float16* __restrict__ vh, _Float16* __restrict__ vl) {
  __shared__ _Float16 ls[32768];
  f32x4 acc[4][4] = {}, accx[4][4] = {};
  int bid = blockIdx.x;
  int sw = (bid & 7) * 96 + (bid >> 3);
  int bm = (sw & 31) * 128, bn = (sw >> 5) * 128;
  gemm128s(xh, xl, Wh, Wl, 1024, 1024, 1024, bm, bn, ls, acc, accx);
  const int tid = threadIdx.x, w = tid >> 6, l = tid & 63, lr = l & 15, lg = l >> 4;
  const int wr = (w >> 1) * 64, wc = (w & 1) * 64;
  #pragma unroll
  for (int m = 0; m < 4; m++) {
    int row0 = bm + wr + m * 16 + lg * 4;
    #pragma unroll
    for (int n = 0; n < 4; n++) {
      int col = bn + wc + n * 16 + lr;
      int mat = col >> 10;
      int c = col & 1023, h = c >> 6, d = c & 63;
      if (mat == 2) {
        int bb = row0 >> 11, ss = row0 & 2047;
        int tile = ss >> 5, kvs = ss & 31;
        f16x4 ph, pl;
        #pragma unroll
        for (int j = 0; j < 4; j++) {
          float v = acc[m][n][j] + accx[m][n][j] * INV_LO;
          _Float16 hh, ll; split16(v, hh, ll);
          ph[j] = hh; pl[j] = ll;
        }
        size_t base = ((size_t)(bb * N_HEADS + h) * 64 + tile) * 2048;
        int off = d * 32 + ((((kvs >> 3) ^ ((d >> 1) & 3)) << 3) | (kvs & 7));
        *(f16x4*)(vh + base + off) = ph;
        *(f16x4*)(vl + base + off) = pl;
      } else if (mat == 1) {
        #pragma unroll
        for (int j = 0; j < 4; j++) {
          float v = acc[m][n][j] + accx[m][n][j] * INV_LO;
          _Float16 hh, ll; split16(v, hh, ll);
          int t = row0 + j, bb = t >> 11, ss = t & 2047;
          int tile = ss >> 5, r = ss & 31;
          size_t base = ((size_t)(bb * N_HEADS + h) * 64 + tile) * 2048;
          int off = r * 64 + ((((d >> 3) ^ (r & 7)) << 3) | (d & 7));
          kh[base + off] = hh; kl[base + off] = ll;
        }
      } else {
        #pragma unroll
        for (int j = 0; j < 4; j++) {
          float v = (acc[m][n][j] + accx[m][n][j] * INV_LO) * QSCALE;
          _Float16 hh, ll; split16(v, hh, ll);
          int t = row0 + j, bb = t >> 11, ss = t & 2047;
          size_t idx = ((size_t)(bb * N_HEADS + h) * SEQ + ss) * 64 + d;
          qh[idx] = hh; ql[idx] = ll;
        }
      }
    }
  }
}

// ---------------- Flash attention: 64q block (4 waves x 16q), KVBLK=32, dbuf gload_lds staging ----------------
__global__ __launch_bounds__(256, 4) void flash_kernel(const _Float16* __restrict__ qhp, const _Float16* __restrict__ qlp,
                                                       const _Float16* __restrict__ khs, const _Float16* __restrict__ kls,
                                                       const _Float16* __restrict__ vhs, const _Float16* __restrict__ vls,
                                                       _Float16* __restrict__ oh, _Float16* __restrict__ ol) {
  __shared__ _Float16 lsKV[2][8192];
  __shared__ _Float16 lsP[4][2][512];
  int wgid = blockIdx.x;
  int xcd = wgid & 7, kk = wgid >> 3;
  int bh = xcd * 4 + (kk >> 5), qt = kk & 31;
  int tid = threadIdx.x, w = tid >> 6, l = tid & 63, lr = l & 15, lg = l >> 4;
  int q0 = qt * 64 + w * 16;
  const _Float16* qhb = qhp + (size_t)bh * SEQ * 64;
  const _Float16* qlb = qlp + (size_t)bh * SEQ * 64;
  f16x8 qfh[2], qfl[2];
  #pragma unroll
  for (int ks = 0; ks < 2; ks++) {
    size_t idx = (size_t)(q0 + lr) * 64 + ks * 32 + lg * 8;
    qfh[ks] = *(const f16x8*)(qhb + idx);
    qfl[ks] = *(const f16x8*)(qlb + idx);
  }
  const _Float16* splane = (w == 0) ? khs : (w == 1) ? kls : (w == 2) ? vhs : vls;
  const _Float16* sbase = splane + (size_t)bh * 131072 + l * 8;

  f32x4 acc[4] = {}, accx[4] = {};
  float mst = -1e30f, lstp = 0.f;

  {
    const _Float16* sp = sbase;
    _Float16* dd = &lsKV[0][w * 2048];
    gload_lds16(sp, dd); gload_lds16(sp + 512, dd + 512);
    gload_lds16(sp + 1024, dd + 1024); gload_lds16(sp + 1536, dd + 1536);
  }
  __syncthreads();

  for (int t = 0; t < 64; t++) {
    int bR = t & 1;
    if (t < 63) {
      const _Float16* sp = sbase + (size_t)(t + 1) * 2048;
      _Float16* dd = &lsKV[bR ^ 1][w * 2048];
      gload_lds16(sp, dd); gload_lds16(sp + 512, dd + 512);
      gload_lds16(sp + 1024, dd + 1024); gload_lds16(sp + 1536, dd + 1536);
    }
    char* bufB = (char*)&lsKV[bR][0];

    // ---- QK^T ----
    f32x4 s[2] = {}, sx[2] = {};
    #pragma unroll
    for (int ks = 0; ks < 2; ks++) {
      f16x8 kfh[2], kfl[2];
      #pragma unroll
      for (int m = 0; m < 2; m++) {
        int off = (m * 16 + lr) * 128 + (((ks * 4 + lg) ^ (lr & 7)) << 4);
        kfh[m] = *(const f16x8*)(bufB + off);
        kfl[m] = *(const f16x8*)(bufB + 4096 + off);
      }
      __builtin_amdgcn_s_setprio(1);
      #pragma unroll
      for (int m = 0; m < 2; m++) {
        s[m]  = __builtin_amdgcn_mfma_f32_16x16x32_f16(kfh[m], qfh[ks], s[m], 0, 0, 0);
        sx[m] = __builtin_amdgcn_mfma_f32_16x16x32_f16(kfh[m], qfl[ks], sx[m], 0, 0, 0);
        sx[m] = __builtin_amdgcn_mfma_f32_16x16x32_f16(kfl[m], qfh[ks], sx[m], 0, 0, 0);
      }
      __builtin_amdgcn_s_setprio(0);
    }

    // ---- softmax (per-lane defer check; deferred l-reduction) ----
    float tm = -3e38f;
    #pragma unroll
    for (int m = 0; m < 2; m++)
      #pragma unroll
      for (int j = 0; j < 4; j++) {
        s[m][j] += sx[m][j] * INV_LO;
        tm = fmaxf(tm, s[m][j]);
      }
    if (!__all(tm - mst <= DTHR)) {
      tm = fmaxf(tm, __shfl_xor(tm, 16));
      tm = fmaxf(tm, __shfl_xor(tm, 32));
      float mnew = fmaxf(mst, tm);
      float corr = exp2f(mst - mnew);
      #pragma unroll
      for (int m2 = 0; m2 < 4; m2++)
        #pragma unroll
        for (int j = 0; j < 4; j++) { acc[m2][j] *= corr; accx[m2][j] *= corr; }
      lstp *= corr;
      mst = mnew;
    }
    #pragma unroll
    for (int m = 0; m < 2; m++) {
      #pragma unroll
      for (int j = 0; j < 4; j++) {
        float p = exp2f(s[m][j] - mst);
        lstp += p;
        s[m][j] = p;
      }
      f16x2 h01, h23, l01, l23;
      split2(s[m][0], s[m][1], h01, l01);
      split2(s[m][2], s[m][3], h23, l23);
      f16x4 ph, pl;
      ph[0] = h01[0]; ph[1] = h01[1]; ph[2] = h23[0]; ph[3] = h23[1];
      pl[0] = l01[0]; pl[1] = l01[1]; pl[2] = l23[0]; pl[3] = l23[1];
      int boff = lr * 64 + ((((m * 2 + (lg >> 1)) ^ ((lr >> 1) & 3)) << 4) | ((lg & 1) * 8));
      *(f16x4*)((char*)&lsP[w][0][0] + boff) = ph;
      *(f16x4*)((char*)&lsP[w][1][0] + boff) = pl;
    }

    // ---- PV ----
    int poff = lr * 64 + ((lg ^ ((lr >> 1) & 3)) << 4);
    f16x8 pfh = *(const f16x8*)((char*)&lsP[w][0][0] + poff);
    f16x8 pfl = *(const f16x8*)((char*)&lsP[w][1][0] + poff);
    __builtin_amdgcn_s_setprio(1);
    #pragma unroll
    for (int m2 = 0; m2 < 4; m2++) {
      int voff = (m2 * 16 + lr) * 64 + ((lg ^ ((lr >> 1) & 3)) << 4);
      f16x8 vfh = *(const f16x8*)(bufB + 8192 + voff);
      f16x8 vfl = *(const f16x8*)(bufB + 12288 + voff);
      acc[m2]  = __builtin_amdgcn_mfma_f32_16x16x32_f16(vfh, pfh, acc[m2], 0, 0, 0);
      accx[m2] = __builtin_amdgcn_mfma_f32_16x16x32_f16(vfh, pfl, accx[m2], 0, 0, 0);
      accx[m2] = __builtin_amdgcn_mfma_f32_16x16x32_f16(vfl, pfh, accx[m2], 0, 0, 0);
    }
    __builtin_amdgcn_s_setprio(0);
    __syncthreads();
  }

  float lst = lstp + __shfl_xor(lstp, 16);
  lst += __shfl_xor(lst, 32);
  float inv = 1.f / lst;
  int b = bh >> 4, h = bh & 15;
  int tkn = b * SEQ + q0 + lr;
  #pragma unroll
  for (int m2 = 0; m2 < 4; m2++) {
    f16x4 ph, pl;
    #pragma unroll
    for (int j = 0; j < 4; j++) {
      float o = (acc[m2][j] + accx[m2][j] * INV_LO) * inv;
      _Float16 hh, ll; split16(o, hh, ll);
      ph[j] = hh; pl[j] = ll;
    }
    size_t idx = (size_t)tkn * D_MODEL + h * 64 + m2 * 16 + lg * 4;
    *(f16x4*)(oh + idx) = ph;
    *(f16x4*)(ol + idx) = pl;
  }
}

// ---------------- O-proj GEMM + residual -> d_out (fp32) ----------------
__global__ __launch_bounds__(256) void gemm_oproj_kernel(const _Float16* __restrict__ ah, const _Float16* __restrict__ al,
                                                         const _Float16* __restrict__ Wh, const _Float16* __restrict__ Wl,
                                                         const float* __restrict__ x, float* __restrict__ out) {
  __shared__ _Float16 ls[32768];
  f32x4 acc[4][4] = {}, accx[4][4] = {};
  int bid = blockIdx.x;
  int sw = (bid & 7) * 32 + (bid >> 3);
  int bm = (sw & 31) * 128, bn = (sw >> 5) * 128;
  gemm128s(ah, al, Wh, Wl, 1024, 1024, 1024, bm, bn, ls, acc, accx);
  const int tid = threadIdx.x, w = tid >> 6, l = tid & 63, lr = l & 15, lg = l >> 4;
  const int wr = (w >> 1) * 64, wc = (w & 1) * 64;
  #pragma unroll
  for (int m = 0; m < 4; m++) {
    int row0 = bm + wr + m * 16 + lg * 4;
    #pragma unroll
    for (int n = 0; n < 4; n++) {
      int col = bn + wc + n * 16 + lr;
      #pragma unroll
      for (int j = 0; j < 4; j++) {
        size_t idx = (size_t)(row0 + j) * D_MODEL + col;
        out[idx] = (acc[m][n][j] + accx[m][n][j] * INV_LO) + x[idx];
      }
    }
  }
}

// ---------------- fused LN2 + xn2(bf16) + gate + top2 (fp32) ----------------
__global__ __launch_bounds__(256) void gate_kernel(const float* __restrict__ x1, const float* __restrict__ Wg,
                                                   const float* __restrict__ g2, const float* __restrict__ b2,
                                                   unsigned short* __restrict__ xn2,
                                                   int* __restrict__ cnt, int* __restrict__ cnt8,
                                                   int* __restrict__ topi, float* __restrict__ topw) {
  int t = blockIdx.x * 4 + (threadIdx.x >> 6);
  int l = threadIdx.x & 63;
  const float* row = x1 + (size_t)t * D_MODEL;
  fx4 v[4];
  float s = 0.f, s2 = 0.f;
  #pragma unroll
  for (int i = 0; i < 4; i++) {
    v[i] = *(const fx4*)(row + l * 16 + i * 4);
    #pragma unroll
    for (int c = 0; c < 4; c++) { s += v[i][c]; s2 += v[i][c] * v[i][c]; }
  }
  #pragma unroll
  for (int off = 1; off < 64; off <<= 1) { s += __shfl_xor(s, off); s2 += __shfl_xor(s2, off); }
  float mu = s * (1.f / 1024.f);
  float var = s2 * (1.f / 1024.f) - mu * mu;
  float rstd = rsqrtf(var + 1e-5f);
  float a8[8] = {0,0,0,0,0,0,0,0};
  #pragma unroll
  for (int i = 0; i < 4; i++) {
    u16x4 ox;
    #pragma unroll
    for (int c = 0; c < 4; c++) {
      int kk = l * 16 + i * 4 + c;
      float xv = (v[i][c] - mu) * rstd * g2[kk] + b2[kk];
      ox[c] = f2bf(xv);
      const float* wr_ = Wg + (size_t)kk * 8;
      fx4 wa = *(const fx4*)wr_;
      fx4 wb = *(const fx4*)(wr_ + 4);
      a8[0] += xv * wa[0]; a8[1] += xv * wa[1]; a8[2] += xv * wa[2]; a8[3] += xv * wa[3];
      a8[4] += xv * wb[0]; a8[5] += xv * wb[1]; a8[6] += xv * wb[2]; a8[7] += xv * wb[3];
    }
    *(u16x4*)(xn2 + (size_t)t * D_MODEL + l * 16 + i * 4) = ox;
  }
  #pragma unroll
  for (int e = 0; e < 8; e++)
    #pragma unroll
    for (int off = 1; off < 64; off <<= 1) a8[e] += __shfl_xor(a8[e], off);
  if (l == 0) {
    int i0 = 0; float v0 = a8[0];
    #pragma unroll
    for (int e = 1; e < 8; e++) if (a8[e] > v0) { v0 = a8[e]; i0 = e; }
    int i1 = -1; float v1 = -3.4e38f;
    #pragma unroll
    for (int e = 0; e < 8; e++) if (e != i0 && a8[e] > v1) { v1 = a8[e]; i1 = e; }
    float p0 = 1.f / (1.f + __expf(v1 - v0));
    topi[t * 2] = i0; topi[t * 2 + 1] = i1;
    topw[t * 2] = p0; topw[t * 2 + 1] = 1.f - p0;
    int seg = t >> 9;
    atomicAdd(&cnt[i0], 1); atomicAdd(&cnt[i1], 1);
    atomicAdd(&cnt8[i0 * 8 + seg], 1); atomicAdd(&cnt8[i1 * 8 + seg], 1);
  }
}

// stable partition of the 8192 (token,k) assignments; block = (expert, 512-token segment)
__global__ __launch_bounds__(256) void scatter_kernel(const int* __restrict__ topi, const int* __restrict__ cnt,
                                                      const int* __restrict__ cnt8,
                                                      int* __restrict__ perm, int* __restrict__ slot_of) {
  int e = blockIdx.x & 7, seg = blockIdx.x >> 3;
  int tid = threadIdx.x;
  __shared__ int basesh;
  __shared__ int wsum[4];
  if (tid == 0) {
    int a = 0;
    for (int i = 0; i < e; i++) a += ((cnt[i] + 63) >> 6) << 6;
    for (int s = 0; s < seg; s++) a += cnt8[e * 8 + s];
    basesh = a;
  }
  __syncthreads();
  int a0 = seg * 1024;
  for (int segi = 0; segi < 1024; segi += 256) {
    int a = a0 + segi + tid;
    int match = (topi[a] == e) ? 1 : 0;
    unsigned long long bal = __ballot(match);
    int wl = tid & 63, wv = tid >> 6;
    int lanepre = __popcll(bal & ((1ULL << wl) - 1ULL));
    if (wl == 0) wsum[wv] = __popcll(bal);
    __syncthreads();
    int wpre = 0;
    for (int i = 0; i < wv; i++) wpre += wsum[i];
    int total = wsum[0] + wsum[1] + wsum[2] + wsum[3];
    if (match) {
      int pos = basesh + wpre + lanepre;
      perm[pos] = a >> 1;
      slot_of[a] = pos;
    }
    __syncthreads();
    if (tid == 0) basesh += total;
    __syncthreads();
  }
}

// ---------------- MoE FFN: 64-token tile, 8 waves, hid in 2 halves, writes y[slot][1024] (bf16) ----------------
__global__ __launch_bounds__(512) void moe_ffn_kernel(const unsigned short* __restrict__ xn2,
                                                      const unsigned short* __restrict__ W1T,
                                                      const unsigned short* __restrict__ W2T,
                                                      const int* __restrict__ cnt,
                                                      const int* __restrict__ perm,
                                                      unsigned short* __restrict__ y) {
  int bid = blockIdx.x;
  int e = -1, lt = bid, off = 0;
  for (int i = 0; i < 8; i++) {
    int nt = (cnt[i] + 63) >> 6;
    if (lt < nt) { e = i; break; }
    lt -= nt; off += nt << 6;
  }
  if (e < 0) return;
  int slot0 = off + lt * 64;

  __shared__ int t_sh[64];
  __shared__ unsigned short lsX[64 * 128];
  __shared__ unsigned short hsh[64 * 264];
  int tid = threadIdx.x, w = tid >> 6, l = tid & 63, lr = l & 15, lg = l >> 4;
  if (tid < 64) t_sh[tid] = perm[slot0 + tid];
  __syncthreads();

  const unsigned short* W1e = W1T + (size_t)e * EHID * D_MODEL;
  const unsigned short* W2e = W2T + (size_t)e * D_MODEL * EHID;

  f32x4 acc2[4][8] = {};
  for (int h = 0; h < 2; h++) {
    f32x4 acc1[4][2] = {};
    for (int kc = 0; kc < 8; kc++) {
      __syncthreads();
      #pragma unroll
      for (int L = 0; L < 2; L++) {
        int u = tid + 512 * L;
        int r = u >> 4, sp = u & 15;
        int cs = (sp & 8) | ((sp & 7) ^ (r & 7));
        gload_lds16(xn2 + (size_t)t_sh[r] * D_MODEL + kc * 128 + cs * 8, (char*)lsX + u * 16);
      }
      __syncthreads();
      #pragma unroll
      for (int kst = 0; kst < 4; kst++) {
        bf16x8 a[4];
        #pragma unroll
        for (int m = 0; m < 4; m++) {
          int row = m * 16 + lr;
          int slot = kst * 4 + lg;
          int cs = (slot & 8) | ((slot & 7) ^ (row & 7));
          a[m] = *(const bf16x8*)((char*)lsX + row * 256 + cs * 16);
        }
        int ko = kc * 128 + kst * 32;
        #pragma unroll
        for (int n = 0; n < 2; n++) {
          bf16x8 bb = *(const bf16x8*)(W1e + (size_t)(h * 256 + w * 32 + n * 16 + lr) * D_MODEL + ko + lg * 8);
          #pragma unroll
          for (int m = 0; m < 4; m++)
            acc1[m][n] = __builtin_amdgcn_mfma_f32_16x16x32_bf16(a[m], bb, acc1[m][n], 0, 0, 0);
        }
      }
    }
    __syncthreads();
    #pragma unroll
    for (int m = 0; m < 4; m++)
      #pragma unroll
      for (int n = 0; n < 2; n++)
        #pragma unroll
        for (int j = 0; j < 4; j++)
          hsh[(m*16 + lg*4 + j) * 264 + w * 32 + n * 16 + lr] = f2bf(fmaxf(acc1[m][n][j], 0.f));
    __syncthreads();
    for (int k2 = 0; k2 < 256; k2 += 32) {
      bf16x8 a2[4];
      #pragma unroll
      for (int m = 0; m < 4; m++) a2[m] = *(const bf16x8*)(hsh + (m*16 + lr) * 264 + k2 + lg * 8);
      #pragma unroll
      for (int n = 0; n < 8; n++) {
        bf16x8 bb = *(const bf16x8*)(W2e + (size_t)(w * 128 + n * 16 + lr) * EHID + h * 256 + k2 + lg * 8);
        #pragma unroll
        for (int m = 0; m < 4; m++)
          acc2[m][n] = __builtin_amdgcn_mfma_f32_16x16x32_bf16(a2[m], bb, acc2[m][n], 0, 0, 0);
      }
    }
  }
  #pragma unroll
  for (int m = 0; m < 4; m++)
    #pragma unroll
    for (int j = 0; j < 4; j++) {
      int r = m * 16 + lg * 4 + j;
      #pragma unroll
      for (int n = 0; n < 8; n++)
        y[(size_t)(slot0 + r) * D_MODEL + w * 128 + n * 16 + lr] = f2bf(acc2[m][n][j]);
    }
}

// ---------------- combine: out[t] += w0*y[s0] + w1*y[s1] (y bf16) ----------------
__global__ __launch_bounds__(256) void combine_kernel(const unsigned short* __restrict__ y, const int* __restrict__ slot_of,
                                                      const float* __restrict__ topw, float* __restrict__ out) {
  int t = blockIdx.x * 4 + (threadIdx.x >> 6);
  int l = threadIdx.x & 63;
  int s0 = slot_of[t * 2], s1 = slot_of[t * 2 + 1];
  float w0 = topw[t * 2], w1 = topw[t * 2 + 1];
  const unsigned short* y0 = y + (size_t)s0 * D_MODEL + l * 16;
  const unsigned short* y1 = y + (size_t)s1 * D_MODEL + l * 16;
  float* o = out + (size_t)t * D_MODEL + l * 16;
  #pragma unroll
  for (int i = 0; i < 4; i++) {
    u16x4 av = *(const u16x4*)(y0 + i * 4);
    u16x4 bv = *(const u16x4*)(y1 + i * 4);
    fx4 d = *(const fx4*)(o + i * 4);
    #pragma unroll
    for (int j = 0; j < 4; j++) d[j] += w0 * bf2f(av[j]) + w1 * bf2f(bv[j]);
    *(fx4*)(o + i * 4) = d;
  }
}

// ---------------- launcher ----------------
#define MB (1u << 20)
extern "C" void kernel_launch(void* const* d_in, const int* in_sizes, int n_in,
                              void* d_out, int out_size, void* d_ws, size_t ws_size,
                              hipStream_t stream) {
  const float* x  = (const float*)d_in[0];
  const float* Wq = (const float*)d_in[1];
  const float* Wk = (const float*)d_in[2];
  const float* Wv = (const float*)d_in[3];
  const float* Wo = (const float*)d_in[4];
  const float* g1 = (const float*)d_in[5];
  const float* b1 = (const float*)d_in[6];
  const float* g2 = (const float*)d_in[7];
  const float* b2 = (const float*)d_in[8];
  const float* Wg = (const float*)d_in[9];
  const float* W1 = (const float*)d_in[10];
  const float* W2 = (const float*)d_in[11];
  float* out = (float*)d_out;

  char* ws = (char*)d_ws;
  _Float16* xn1h = (_Float16*)(ws + 0*MB);     // later aliased as attn hi plane
  _Float16* xn1l = (_Float16*)(ws + 8*MB);     // later aliased as attn lo plane
  _Float16* Wqkh = (_Float16*)(ws + 16*MB);
  _Float16* Wqkl = (_Float16*)(ws + 22*MB);
  _Float16* Woh  = (_Float16*)(ws + 28*MB);
  _Float16* Wol  = (_Float16*)(ws + 30*MB);
  _Float16* qhb  = (_Float16*)(ws + 32*MB);
  _Float16* qlb  = (_Float16*)(ws + 40*MB);
  _Float16* khb  = (_Float16*)(ws + 48*MB);
  _Float16* klb  = (_Float16*)(ws + 56*MB);
  _Float16* vhb  = (_Float16*)(ws + 64*MB);
  _Float16* vlb  = (_Float16*)(ws + 72*MB);
  unsigned short* xn2 = (unsigned short*)(ws + 80*MB);
  unsigned short* W1T = (unsigned short*)(ws + 88*MB);
  unsigned short* W2T = (unsigned short*)(ws + 96*MB);
  char* misc = ws + 104*MB;
  int*   topi    = (int*)(misc);
  float* topw    = (float*)(misc + 32768);
  int*   slot_of = (int*)(misc + 65536);
  int*   cnt     = (int*)(misc + 98304);
  int*   cnt8    = (int*)(misc + 98368);
  int*   perm    = (int*)(misc + 98688);
  unsigned short* ybuf = (unsigned short*)(ws + 32*MB);   // bf16 y, aliases q/k/v (dead after flash)
  _Float16* attnh = xn1h;
  _Float16* attnl = xn1l;

  // fused LN1 + weight prep + routing init (one launch)
  prep_ln_kernel<<<16419, 256, 0, stream>>>(x, g1, b1, xn1h, xn1l,
                                            Wq, Wk, Wv, Wo, W1, W2,
                                            Wqkh, Wqkl, Woh, Wol, W1T, W2T, cnt, cnt8, perm);

  // attention path (split fp16, ~fp32 accuracy)
  gemm_qkv_kernel<<<768, 256, 0, stream>>>(xn1h, xn1l, Wqkh, Wqkl, qhb, qlb, khb, klb, vhb, vlb);
  flash_kernel<<<1024, 256, 0, stream>>>(qhb, qlb, khb, klb, vhb, vlb, attnh, attnl);
  gemm_oproj_kernel<<<256, 256, 0, stream>>>(attnh, attnl, Woh, Wol, x, out);

  // MoE path
  gate_kernel<<<1024, 256, 0, stream>>>(out, Wg, g2, b2, xn2, cnt, cnt8, topi, topw);
  scatter_kernel<<<64, 256, 0, stream>>>(topi, cnt, cnt8, perm, slot_of);
  moe_ffn_kernel<<<136, 512, 0, stream>>>(xn2, W1T, W2T, cnt, perm, ybuf);
  combine_kernel<<<1024, 256, 0, stream>>>(ybuf, slot_of, topw, out);

  (void)in_sizes; (void)n_in; (void)out_size; (void)ws_size;
}